// Round 9
// baseline (125.630 us; speedup 1.0000x reference)
//
#include <hip/hip_runtime.h>
#include <hip/hip_fp16.h>

// Radon forward: x [4,1,256,256] f32, thetas[180], positions[256] -> out [4,1,180,256] f32
// T=363 samples/ray; support-clipped (samples outside bilinear support contribute 0).
//
// Round 9: vertical-pair f16 LDS layout. D[r][c] = (img[r][c], img[r+1][c]) packed
// half2 -> ONE ds_read2_b32 per sample fetches all 4 bilinear taps (2 bank accesses
// vs 4). Quarter-split per block (4 z-blocks, thresholds at image 64q) keeps LDS at
// ~75KB -> 2 blocks/CU. Ownership partition = proven round-8 scheme generalized to
// 4 edges; S_q computed from IDENTICAL float expressions in all 4 blocks -> exact
// partition. Edge overflow reads land on zero pairs (border predicate + wy=0 trick).

#define NB   4
#define NA   180
#define NP   256
#define GANG 3       // angles per block; regime boundaries 45,135 are multiples of 3
#define NSEG 4
#define NQ   4       // quarters

// Regime A (row-split):  67 pair-rows x stride 261 = 17487 dw
// Regime B (col-split): 258 pair-rows x stride  69 = 17802 dw
#define IMG_DW  17802
#define RED_OFF (IMG_DW * 4)               // 71208
#define SMEM_BYTES (RED_OFF + NP * NSEG * 4)  // 75304 ; x2 blocks = 147KB <= 160KB/CU

__device__ __forceinline__ unsigned pack_h2(float a, float b) {
    __half2 h = __halves2half2(__float2half_rn(a), __float2half_rn(b));
    return *reinterpret_cast<unsigned*>(&h);
}

template<int STRIDE>
__device__ __forceinline__ float ray_accum(
    const unsigned int* __restrict__ imgw,
    float bxr, float byr, float nsv, float cv,
    float xlo, float xhi, float ylo, float yhi,
    int tlo, int thi, int seg)
{
    float acc = 0.f;
    int   t  = tlo + seg;
    float pxu = fmaf((float)t - 181.0f, nsv, bxr);
    float pyu = fmaf((float)t - 181.0f, cv,  byr);
    const float dpx = 4.0f * nsv;
    const float dpy = 4.0f * cv;
    #pragma unroll 4
    for (; t < thi; t += 4) {
        float px = __builtin_amdgcn_fmed3f(pxu, xlo, xhi);
        float py = __builtin_amdgcn_fmed3f(pyu, ylo, yhi);
        pxu += dpx;
        pyu += dpy;
        const float fx = floorf(px);
        const float fy = floorf(py);
        const float wx = px - fx;
        const float wy = py - fy;
        const int ad = (int)fmaf(fy, (float)STRIDE, fx);   // pair-dword index
        const unsigned q0 = imgw[ad];        // (top,bot) at col ix   -> ds_read2_b32
        const unsigned q1 = imgw[ad + 1];    // (top,bot) at col ix+1
        // transpose pairs: A=(top0,top1), B=(bot0,bot1)
        unsigned A = __builtin_amdgcn_perm(q1, q0, 0x05040100u);
        unsigned B = __builtin_amdgcn_perm(q1, q0, 0x07060302u);
        const __half2 hA = *reinterpret_cast<__half2*>(&A);
        const __half2 hB = *reinterpret_cast<__half2*>(&B);
        const __half2 wy2 = __half2half2(__float2half_rn(wy));
        const __half2 V = __hfma2(wy2, __hsub2(hB, hA), hA);  // vertical lerp, both cols
        const float vlo = __half2float(__low2half(V));
        const float vhi = __half2float(__high2half(V));
        acc = fmaf(wx, vhi - vlo, acc + vlo);
    }
    return acc;
}

extern "C" __global__ __launch_bounds__(1024)
void radon_fwd(const float* __restrict__ x,
               const float* __restrict__ thetas,
               const float* __restrict__ positions,
               float* __restrict__ out)
{
    extern __shared__ unsigned char smem[];
    unsigned int* imgw = (unsigned int*)smem;
    float*        red  = (float*)(smem + RED_OFF);

    const int grp = blockIdx.x;
    const int b   = blockIdx.y;
    const int qz  = blockIdx.z;            // quarter 0..3
    const int a0  = grp * GANG;
    const bool regA = (a0 < 45) || (a0 >= 135);
    const int tid = threadIdx.x + (threadIdx.y << 8);
    const float* __restrict__ xb = x + b * 65536;

    // --- stage quarter as vertical-pair f16 dwords (border predicate -> zeros) ---
    if (regA) {
        // pair-row r: lo = img[64q-1+r], hi = img[64q+r]; col c: img col c-2
        for (int d = tid; d < 67 * 261; d += 1024) {
            const int r = d / 261, c = d - r * 261;
            const int gr = 64 * qz + r - 1;
            const int gc = c - 2;
            const bool gok = (gc >= 0) & (gc < 256);
            const float v0 = (gok && gr >= 0   && gr < 256) ? xb[gr * 256 + gc]       : 0.f;
            const float v1 = (gok && gr >= -1  && gr < 255) ? xb[(gr + 1) * 256 + gc] : 0.f;
            imgw[d] = pack_h2(v0, v1);
        }
    } else {
        // pair-row r: lo = img[r-1], hi = img[r]; col c: img col 64q+c-2
        for (int d = tid; d < 258 * 69; d += 1024) {
            const int r = d / 69, c = d - r * 69;
            const int gr = r - 1;
            const int gc = 64 * qz + c - 2;
            const bool gok = (gc >= 0) & (gc < 256);
            const float v0 = (gok && gr >= 0  && gr < 256) ? xb[gr * 256 + gc]       : 0.f;
            const float v1 = (gok && gr >= -1 && gr < 255) ? xb[(gr + 1) * 256 + gc] : 0.f;
            imgw[d] = pack_h2(v0, v1);
        }
    }
    __syncthreads();

    // --- clamp windows (rebased local alloc coords) ---
    float xlo, xhi, ylo, yhi;
    if (regA) { xlo = 1.f; xhi = 258.f;       ylo = 0.f; yhi = 66.f;  }
    else      { xlo = 1.f; xhi = 66.984375f;  ylo = 0.f; yhi = 257.f; }

    const int   p   = threadIdx.x;
    const int   seg = threadIdx.y;
    const float s   = positions[p];

    float accs[GANG];
    for (int g = 0; g < GANG; ++g) {
        const float th  = thetas[a0 + g];
        const float cv  = cosf(th);
        const float sv  = sinf(th);
        const float nsv = -sv;
        const float bx2 = fmaf(s, cv, 129.5f);   // alloc-x base (col offset +2)
        const float by1 = fmaf(s, sv, 128.5f);   // alloc-y base (row offset +1)

        // --- 4-way ownership partition; S[] identical in all 4 quarter-blocks ---
        const float slope = regA ? cv : nsv;     // |slope| >= 0.707 by regime choice
        const float base  = regA ? by1 : bx2;
        const float off   = regA ? 1.0f : 2.0f;  // thr_q = 64q + off (alloc coords)
        float S[3];
        #pragma unroll
        for (int i = 0; i < 3; ++i) {
            const float thr = 64.0f * (float)(i + 1) + off;
            const float ts  = 181.0f + (thr - base) / slope;
            const float Sf  = (slope > 0.f) ? ceilf(ts) : (floorf(ts) + 1.0f);
            S[i] = fmaxf(0.f, fminf(364.f, Sf));
        }
        int lo, hi;
        if (slope > 0.f) {
            lo = (qz == 0) ? 0   : (int)S[qz - 1];
            hi = (qz == 3) ? 364 : (int)S[qz];
        } else {
            lo = (qz == 3) ? 0   : (int)S[qz];
            hi = (qz == 0) ? 364 : (int)S[qz - 1];
        }

        // --- support clip (over-wide by 1 each side; outside-support samples
        //     read exact zeros via border pairs) ---
        const float msx = (fabsf(sv) < 1e-7f) ? copysignf(1e-7f, sv) : sv;
        const float mcy = (fabsf(cv) < 1e-7f) ? copysignf(1e-7f, cv) : cv;
        const float invx = -1.0f / msx;
        const float invy =  1.0f / mcy;
        const float ux1 = (1.0f   - bx2) * invx;
        const float ux2 = (258.0f - bx2) * invx;
        const float uy1 = (0.0f   - by1) * invy;
        const float uy2 = (257.0f - by1) * invy;
        const float ulo = fmaxf(fminf(ux1, ux2), fminf(uy1, uy2));
        const float uhi = fminf(fmaxf(ux1, ux2), fmaxf(uy1, uy2));
        const float tbf = ceilf(ulo + 181.0f) - 1.0f;
        const float tef = floorf(uhi + 181.0f) + 2.0f;
        const int tb = (int)fmaxf((float)lo, fminf(364.0f, tbf));
        const int te = (int)fminf((float)hi, fmaxf(0.0f,  tef));

        const float bxr = regA ? bx2 : (bx2 - 64.0f * (float)qz);
        const float byr = regA ? (by1 - 64.0f * (float)qz) : by1;
        accs[g] = regA
            ? ray_accum<261>(imgw, bxr, byr, nsv, cv, xlo, xhi, ylo, yhi, tb, te, seg)
            : ray_accum< 69>(imgw, bxr, byr, nsv, cv, xlo, xhi, ylo, yhi, tb, te, seg);
    }

    // --- reduce 4 segs, then one atomicAdd per (g,p) (4 adds/output total) ---
    for (int g = 0; g < GANG; ++g) {
        __syncthreads();
        red[(seg << 8) + p] = accs[g];
        __syncthreads();
        if (seg == 0) {
            float r4 = red[p] + red[256 + p] + red[512 + p] + red[768 + p];
            atomicAdd(&out[b * (NA * NP) + (a0 + g) * NP + p], r4);
        }
    }
}

extern "C" void kernel_launch(void* const* d_in, const int* in_sizes, int n_in,
                              void* d_out, int out_size, void* d_ws, size_t ws_size,
                              hipStream_t stream) {
    const float* x         = (const float*)d_in[0];
    const float* thetas    = (const float*)d_in[1];
    const float* positions = (const float*)d_in[2];
    float* out = (float*)d_out;

    hipFuncSetAttribute((const void*)radon_fwd,
                        hipFuncAttributeMaxDynamicSharedMemorySize, SMEM_BYTES);

    // output accumulated via atomics -> zero it first (async, capture-safe)
    hipMemsetAsync(d_out, 0, (size_t)out_size * sizeof(float), stream);

    dim3 grid(NA / GANG, NB, NQ);   // 60 x 4 x 4 = 960 blocks
    dim3 block(NP, NSEG);           // 1024 threads
    radon_fwd<<<grid, block, SMEM_BYTES, stream>>>(x, thetas, positions, out);
}

// Round 10
// 116.061 us; speedup vs baseline: 1.0825x; 1.0825x over previous
//
#include <hip/hip_runtime.h>
#include <hip/hip_fp16.h>

// Radon forward: x [4,1,256,256] f32, thetas[180], positions[256] -> out [4,1,180,256] f32
// T=363 samples/ray (run 364; extras fall in zero border).
//
// Round 10 = round-8 proven structure (half-split, 2 atomicAdds/output, support
// clip, seg-strided t) + round-9 proven inner loop (vertical-pair f16 LDS:
// P[r][c] = (img[row][col], img[row+1][col]) -> ONE ds_read2_b32 per sample).
// Pair storage is 2x -> ~140KB LDS -> 1 block/CU (round 6 showed occupancy
// above 16 waves/CU is not the limiter).
//
// Coordinates: image space. px = 127.5 + s*cos - tt*sin, py = 127.5 + s*sin + tt*cos,
// tt = t - 181. Regime A (|cos|>=0.707): row-split at py=128. Regime B: col-split
// at px=128. Local coords: px_loc = px - CbX, py_loc = py - CbY.
// All reachable clamp edges land on exact-zero pairs (verified per edge).

#define NB   4
#define NA   180
#define NP   256
#define GANG 3
#define NSEG 4

#define STRIDE_A 261   // c = px_loc in [0,260]; rows r = py_loc in [0,134]
#define ROWS_A   135
#define STRIDE_B 138   // c = px_loc in [0,137]; rows r = py_loc in [0,258]
#define ROWS_B   259
#define IMG_DW   (ROWS_B * STRIDE_B)          // 35742 >= 135*261=35235
#define RED_OFF  (IMG_DW * 4)                 // 142968
#define SMEM_BYTES (RED_OFF + NP * NSEG * 4)  // 147064 <= 160KB -> 1 block/CU

__device__ __forceinline__ unsigned pack_h2(float a, float b) {
    __half2 h = __halves2half2(__float2half_rn(a), __float2half_rn(b));
    return *reinterpret_cast<unsigned*>(&h);
}

template<int STRIDE>
__device__ __forceinline__ float ray_accum(
    const unsigned int* __restrict__ imgw,
    float bxr, float byr, float nsv, float cv,
    float xlo, float xhi, float ylo, float yhi,
    int tlo, int thi, int seg)
{
    float acc = 0.f;
    int   t  = tlo + seg;
    float pxu = fmaf((float)t - 181.0f, nsv, bxr);
    float pyu = fmaf((float)t - 181.0f, cv,  byr);
    const float dpx = 4.0f * nsv;
    const float dpy = 4.0f * cv;
    #pragma unroll 4
    for (; t < thi; t += 4) {
        float px = __builtin_amdgcn_fmed3f(pxu, xlo, xhi);
        float py = __builtin_amdgcn_fmed3f(pyu, ylo, yhi);
        pxu += dpx;
        pyu += dpy;
        const float fx = floorf(px);
        const float fy = floorf(py);
        const float wx = px - fx;
        const float wy = py - fy;
        const int ad = (int)fmaf(fy, (float)STRIDE, fx);   // pair-dword index
        const unsigned q0 = imgw[ad];        // (top,bot)@col ix  -> ds_read2_b32
        const unsigned q1 = imgw[ad + 1];    // (top,bot)@col ix+1
        unsigned A = __builtin_amdgcn_perm(q1, q0, 0x05040100u);  // tops
        unsigned B = __builtin_amdgcn_perm(q1, q0, 0x07060302u);  // bottoms
        const __half2 hA = *reinterpret_cast<__half2*>(&A);
        const __half2 hB = *reinterpret_cast<__half2*>(&B);
        const __half2 wy2 = __half2half2(__float2half_rn(wy));
        const __half2 V = __hfma2(wy2, __hsub2(hB, hA), hA);
        const float vlo = __half2float(__low2half(V));
        const float vhi = __half2float(__high2half(V));
        acc = fmaf(wx, vhi - vlo, acc + vlo);
    }
    return acc;
}

extern "C" __global__ __launch_bounds__(1024)
void radon_fwd(const float* __restrict__ x,
               const float* __restrict__ thetas,
               const float* __restrict__ positions,
               float* __restrict__ out)
{
    extern __shared__ unsigned char smem[];
    unsigned int* imgw = (unsigned int*)smem;
    float*        red  = (float*)(smem + RED_OFF);

    const int grp  = blockIdx.x;
    const int b    = blockIdx.y;
    const int half = blockIdx.z;
    const int a0   = grp * GANG;
    const bool regA = (a0 < 45) || (a0 >= 135);
    const int tid = threadIdx.x + (threadIdx.y << 8);
    const float* __restrict__ xb = x + b * 65536;
    const float4* __restrict__ xb4 = (const float4*)xb;

    // --- zero fill (borders + unwritten cols become exact-zero pairs) ---
    for (int i = tid; i < IMG_DW; i += 1024) imgw[i] = 0u;
    __syncthreads();

    // --- stage half image as vertical pairs, float4-vectorized ---
    if (regA) {
        // P[r][c] = (img[Fb+r][c-2], img[Fb+r+1][c-2]); half0 Fb=-2, half1 Fb=122
        const int Fb = half ? 122 : -2;
        for (int d = tid; d < ROWS_A * 64; d += 1024) {
            const int r  = d >> 6;
            const int j  = d & 63;                 // float4 col block: cols 4j..4j+3
            const int R0 = Fb + r, R1 = R0 + 1;
            const int r0c = min(max(R0, 0), 255), r1c = min(max(R1, 0), 255);
            const float4 f0 = xb4[r0c * 64 + j];
            const float4 f1 = xb4[r1c * 64 + j];
            const bool m0 = ((unsigned)R0 < 256u), m1 = ((unsigned)R1 < 256u);
            const float t0x = m0 ? f0.x : 0.f, t0y = m0 ? f0.y : 0.f,
                        t0z = m0 ? f0.z : 0.f, t0w = m0 ? f0.w : 0.f;
            const float t1x = m1 ? f1.x : 0.f, t1y = m1 ? f1.y : 0.f,
                        t1z = m1 ? f1.z : 0.f, t1w = m1 ? f1.w : 0.f;
            const int cb = r * STRIDE_A + 4 * j + 2;
            imgw[cb + 0] = pack_h2(t0x, t1x);
            imgw[cb + 1] = pack_h2(t0y, t1y);
            imgw[cb + 2] = pack_h2(t0z, t1z);
            imgw[cb + 3] = pack_h2(t0w, t1w);
        }
    } else {
        // P[r][c] = (img[r-2][col], img[r-1][col]); half0 col=c-2, half1 col=c+120
        for (int d = tid; d < ROWS_B * 34; d += 1024) {
            const int r = d / 34;
            const int j = d - r * 34;              // 0..33
            const int R0 = r - 2, R1 = r - 1;
            const int r0c = min(max(R0, 0), 255), r1c = min(max(R1, 0), 255);
            const int col4 = j + (half ? 30 : 0);  // cols 4*col4..4*col4+3
            const float4 f0 = xb4[r0c * 64 + col4];
            const float4 f1 = xb4[r1c * 64 + col4];
            const bool m0 = ((unsigned)R0 < 256u), m1 = ((unsigned)R1 < 256u);
            const float t0x = m0 ? f0.x : 0.f, t0y = m0 ? f0.y : 0.f,
                        t0z = m0 ? f0.z : 0.f, t0w = m0 ? f0.w : 0.f;
            const float t1x = m1 ? f1.x : 0.f, t1y = m1 ? f1.y : 0.f,
                        t1z = m1 ? f1.z : 0.f, t1w = m1 ? f1.w : 0.f;
            const int cb = r * STRIDE_B + 4 * j + (half ? 0 : 2);
            imgw[cb + 0] = pack_h2(t0x, t1x);
            imgw[cb + 1] = pack_h2(t0y, t1y);
            imgw[cb + 2] = pack_h2(t0z, t1z);
            imgw[cb + 3] = pack_h2(t0w, t1w);
        }
    }
    __syncthreads();

    // --- clamp windows (local coords); every reachable clamp edge = zero pair ---
    float xlo, xhi, ylo, yhi, CbX, CbY;
    if (regA) {
        xlo = 0.f; xhi = 259.0f;
        ylo = 0.f; yhi = 134.984375f;
        CbX = -2.f; CbY = half ? 122.f : -2.f;
    } else {
        xlo = 0.f; xhi = 136.984375f;
        ylo = 0.f; yhi = 258.984375f;
        CbX = half ? 120.f : -2.f; CbY = -2.f;
    }

    const int   p   = threadIdx.x;
    const int   seg = threadIdx.y;
    const float s   = positions[p];

    float accs[GANG];
    for (int g = 0; g < GANG; ++g) {
        const float th  = thetas[a0 + g];
        const float cv  = cosf(th);
        const float sv  = sinf(th);
        const float nsv = -sv;
        const float bxI = fmaf(s, cv, 127.5f);
        const float byI = fmaf(s, sv, 127.5f);

        // ownership split at 128 (image coords); IDENTICAL float expr both halves
        const float slope = regA ? cv : nsv;      // |slope| >= 0.707 in regime
        const float base  = regA ? byI : bxI;
        const float tstar = 181.0f + (128.0f - base) / slope;
        const float Sf    = (slope > 0.f) ? ceilf(tstar) : (floorf(tstar) + 1.0f);
        const int   S     = (int)fmaxf(0.f, fminf(364.f, Sf));
        const bool  h0Low = (slope > 0.f);
        const int lo = ((half == 0) == h0Low) ? 0 : S;
        const int hi = ((half == 0) == h0Low) ? S : 364;

        // support clip, image window [-2,257] both axes; widened 1 sample/side
        const float msx = (fabsf(sv) < 1e-7f) ? copysignf(1e-7f, sv) : sv;
        const float mcy = (fabsf(cv) < 1e-7f) ? copysignf(1e-7f, cv) : cv;
        const float invx = -1.0f / msx;
        const float invy =  1.0f / mcy;
        const float ux1 = (-2.0f  - bxI) * invx;
        const float ux2 = (257.0f - bxI) * invx;
        const float uy1 = (-2.0f  - byI) * invy;
        const float uy2 = (257.0f - byI) * invy;
        const float ulo = fmaxf(fminf(ux1, ux2), fminf(uy1, uy2));
        const float uhi = fminf(fmaxf(ux1, ux2), fmaxf(uy1, uy2));
        const float tbf = ceilf(ulo + 181.0f) - 1.0f;
        const float tef = floorf(uhi + 181.0f) + 2.0f;
        const int tb = (int)fmaxf((float)lo, fminf(364.0f, tbf));
        const int te = (int)fminf((float)hi, fmaxf(0.0f,  tef));

        const float bxr = bxI - CbX;
        const float byr = byI - CbY;
        accs[g] = regA
            ? ray_accum<STRIDE_A>(imgw, bxr, byr, nsv, cv, xlo, xhi, ylo, yhi, tb, te, seg)
            : ray_accum<STRIDE_B>(imgw, bxr, byr, nsv, cv, xlo, xhi, ylo, yhi, tb, te, seg);
    }

    // --- reduce 4 segs, one atomicAdd per (g,p) (2 adds/output total) ---
    for (int g = 0; g < GANG; ++g) {
        __syncthreads();
        red[(seg << 8) + p] = accs[g];
        __syncthreads();
        if (seg == 0) {
            float r4 = red[p] + red[256 + p] + red[512 + p] + red[768 + p];
            atomicAdd(&out[b * (NA * NP) + (a0 + g) * NP + p], r4);
        }
    }
}

extern "C" void kernel_launch(void* const* d_in, const int* in_sizes, int n_in,
                              void* d_out, int out_size, void* d_ws, size_t ws_size,
                              hipStream_t stream) {
    const float* x         = (const float*)d_in[0];
    const float* thetas    = (const float*)d_in[1];
    const float* positions = (const float*)d_in[2];
    float* out = (float*)d_out;

    hipFuncSetAttribute((const void*)radon_fwd,
                        hipFuncAttributeMaxDynamicSharedMemorySize, SMEM_BYTES);

    hipMemsetAsync(d_out, 0, (size_t)out_size * sizeof(float), stream);

    dim3 grid(NA / GANG, NB, 2);   // 60 x 4 x 2 = 480 blocks
    dim3 block(NP, NSEG);          // 1024 threads
    radon_fwd<<<grid, block, SMEM_BYTES, stream>>>(x, thetas, positions, out);
}